// Round 1
// baseline (476.620 us; speedup 1.0000x reference)
//
#include <hip/hip_runtime.h>

#define BSZ 4
#define TT 2048
#define NH 16
#define HD 64
#define HID 1024
#define BT 8192   // BSZ*TT
#define BH 64     // BSZ*NH

typedef unsigned short u16;
typedef unsigned int u32;
typedef __attribute__((ext_vector_type(4))) float f32x4;
typedef __attribute__((ext_vector_type(8))) short bf16x8;

__device__ __forceinline__ u16 f2bf(float f) {
    union { float f; u32 u; } x; x.f = f;
    u32 r = x.u + 0x7FFFu + ((x.u >> 16) & 1u);
    return (u16)(r >> 16);
}
__device__ __forceinline__ float bf2f(u16 h) {
    union { u32 u; float f; } x; x.u = ((u32)h) << 16;
    return x.f;
}

// ---------------- cast fp32 -> bf16 (vectorized x4) ----------------
__global__ __launch_bounds__(256) void cast_kernel(const float* __restrict__ src,
                                                   u16* __restrict__ dst, int n4) {
    int i = blockIdx.x * 256 + threadIdx.x;
    if (i >= n4) return;
    f32x4 v = *(const f32x4*)(src + (size_t)i * 4);
    uint2 u;
    u.x = (u32)f2bf(v[0]) | ((u32)f2bf(v[1]) << 16);
    u.y = (u32)f2bf(v[2]) | ((u32)f2bf(v[3]) << 16);
    *(uint2*)(dst + (size_t)i * 4) = u;
}

// ---------------- GEMM: C[m,n] = sum_k A[m,k]*W[n,k], bf16 in, fp32 acc ----------------
// MODE 0: qkv -> scatter bf16 into q/k/v (B,H,T,D) layouts (N=3072)
// MODE 1: out -> fp32 C row-major (N=1024)
template<int MODE>
__global__ __launch_bounds__(256)
void gemm_bt(const u16* __restrict__ A, const u16* __restrict__ W,
             float* __restrict__ Cf, u16* __restrict__ qo,
             u16* __restrict__ ko, u16* __restrict__ vo) {
    __shared__ u16 As[128 * 72];
    __shared__ u16 Bs[128 * 72];
    const int tid  = threadIdx.x;
    const int wv   = tid >> 6, lane = tid & 63;
    const int lrow = lane & 15, lk = lane >> 4;
    const int wm   = (wv & 1) * 64, wn = (wv >> 1) * 64;
    const int m0   = blockIdx.x * 128, n0 = blockIdx.y * 128;
    const int srow = tid >> 3, scol = (tid & 7) * 8;

    f32x4 acc[4][4] = {};

    for (int kk = 0; kk < HID; kk += 64) {
        #pragma unroll
        for (int i = 0; i < 4; ++i) {
            int r = srow + 32 * i;
            *(f32x4*)&As[r * 72 + scol] = *(const f32x4*)&A[(size_t)(m0 + r) * HID + kk + scol];
            *(f32x4*)&Bs[r * 72 + scol] = *(const f32x4*)&W[(size_t)(n0 + r) * HID + kk + scol];
        }
        __syncthreads();
        #pragma unroll
        for (int k0 = 0; k0 < 64; k0 += 32) {
            bf16x8 af[4], bfr[4];
            #pragma unroll
            for (int i = 0; i < 4; ++i)
                af[i] = *(const bf16x8*)&As[(wm + i * 16 + lrow) * 72 + k0 + lk * 8];
            #pragma unroll
            for (int j = 0; j < 4; ++j)
                bfr[j] = *(const bf16x8*)&Bs[(wn + j * 16 + lrow) * 72 + k0 + lk * 8];
            #pragma unroll
            for (int i = 0; i < 4; ++i)
                #pragma unroll
                for (int j = 0; j < 4; ++j)
                    acc[i][j] = __builtin_amdgcn_mfma_f32_16x16x32_bf16(af[i], bfr[j], acc[i][j], 0, 0, 0);
        }
        __syncthreads();
    }

    if (MODE == 0) {
        #pragma unroll
        for (int i = 0; i < 4; ++i) {
            #pragma unroll
            for (int j = 0; j < 4; ++j) {
                int nb   = n0 + wn + j * 16;
                int proj = nb >> 10;
                int nl   = nb & 1023;
                int h    = nl >> 6;
                int d    = (nl & 63) + lrow;
                u16* dst = (proj == 0) ? qo : ((proj == 1) ? ko : vo);
                #pragma unroll
                for (int r = 0; r < 4; ++r) {
                    int m = m0 + wm + i * 16 + lk * 4 + r;
                    int b = m >> 11, t = m & 2047;
                    dst[(((size_t)(b * NH + h)) * TT + t) * HD + d] = f2bf(acc[i][j][r]);
                }
            }
        }
    } else {
        #pragma unroll
        for (int i = 0; i < 4; ++i)
            #pragma unroll
            for (int j = 0; j < 4; ++j)
                #pragma unroll
                for (int r = 0; r < 4; ++r) {
                    int m = m0 + wm + i * 16 + lk * 4 + r;
                    int n = n0 + wn + j * 16 + lrow;
                    Cf[(size_t)m * HID + n] = acc[i][j][r];
                }
    }
}

// ---------------- RoPE in-place on q,k (B,H,T,D) bf16; folds 1/sqrt(D) into q ------------
__global__ __launch_bounds__(256) void rope_kernel(u16* __restrict__ q, u16* __restrict__ k,
                                                   const float* __restrict__ cosT,
                                                   const float* __restrict__ sinT) {
    int tid = blockIdx.x * 256 + threadIdx.x;   // BH*T*32 threads
    int d  = tid & 31;
    int t  = (tid >> 5) & 2047;
    int bh = tid >> 16;
    size_t base = ((size_t)bh * TT + t) * HD + d;
    float c = cosT[t * HD + d], s = sinT[t * HD + d];
    float q1 = bf2f(q[base]), q2 = bf2f(q[base + 32]);
    q[base]      = f2bf((q1 * c - q2 * s) * 0.125f);
    q[base + 32] = f2bf((q2 * c + q1 * s) * 0.125f);
    float k1 = bf2f(k[base]), k2 = bf2f(k[base + 32]);
    k[base]      = f2bf(k1 * c - k2 * s);
    k[base + 32] = f2bf(k2 * c + k1 * s);
}

// ---------------- V transpose (B,H,T,D) -> (B,H,D,T) ----------------
__global__ __launch_bounds__(256) void transpose_v(const u16* __restrict__ v, u16* __restrict__ vt) {
    __shared__ u16 tile[64 * 72];
    const int tid = threadIdx.x;
    const int bh = blockIdx.y, t0 = blockIdx.x * 64;
    #pragma unroll
    for (int i = 0; i < 2; ++i) {
        int c = tid + i * 256, r = c >> 3, c8 = (c & 7) * 8;
        *(f32x4*)&tile[r * 72 + c8] = *(const f32x4*)&v[((size_t)bh * TT + t0 + r) * HD + c8];
    }
    __syncthreads();
    #pragma unroll
    for (int i = 0; i < 2; ++i) {
        int c = tid + i * 256, d = c >> 3, t8 = (c & 7) * 8;
        union { f32x4 v4; u16 u[8]; } u;
        #pragma unroll
        for (int j = 0; j < 8; ++j) u.u[j] = tile[(t8 + j) * 72 + d];
        *(f32x4*)&vt[((size_t)bh * HD + d) * TT + t0 + t8] = u.v4;
    }
}

// ---------------- Flash attention: 128 q-rows/block, BN=64, online softmax ----------------
__global__ __launch_bounds__(256)
void attn_kernel(const u16* __restrict__ q, const u16* __restrict__ k,
                 const u16* __restrict__ vt, u16* __restrict__ o) {
    __shared__ u16 Ks[64 * 72];
    __shared__ u16 Vts[64 * 72];
    __shared__ u16 PQs[128 * 72];   // Q staging, then per-wave P regions (32 rows each)
    const int tid  = threadIdx.x;
    const int w    = tid >> 6, lane = tid & 63;
    const int lrow = lane & 15, lk = lane >> 4;
    const int bh   = blockIdx.y;
    const int q0   = blockIdx.x * 128;
    const size_t hb = (size_t)bh * TT * HD;

    // stage Q tile (128x64)
    #pragma unroll
    for (int i = 0; i < 4; ++i) {
        int c = tid + i * 256, r = c >> 3, c8 = (c & 7) * 8;
        *(f32x4*)&PQs[r * 72 + c8] = *(const f32x4*)&q[hb + (size_t)(q0 + r) * HD + c8];
    }
    __syncthreads();
    bf16x8 qf[2][2];
    #pragma unroll
    for (int mt = 0; mt < 2; ++mt)
        #pragma unroll
        for (int kq = 0; kq < 2; ++kq)
            qf[mt][kq] = *(const bf16x8*)&PQs[(w * 32 + mt * 16 + lrow) * 72 + kq * 32 + lk * 8];

    f32x4 oacc[2][4] = {};
    float mi[2][4], li[2][4];
    #pragma unroll
    for (int mt = 0; mt < 2; ++mt)
        #pragma unroll
        for (int r = 0; r < 4; ++r) { mi[mt][r] = -1e30f; li[mt][r] = 0.f; }

    const int rbase = q0 + w * 32;

    for (int n0 = 0; n0 < q0 + 128; n0 += 64) {
        __syncthreads();
        #pragma unroll
        for (int i = 0; i < 2; ++i) {
            int c = tid + i * 256, r = c >> 3, c8 = (c & 7) * 8;
            *(f32x4*)&Ks[r * 72 + c8]  = *(const f32x4*)&k[hb + (size_t)(n0 + r) * HD + c8];
            *(f32x4*)&Vts[r * 72 + c8] = *(const f32x4*)&vt[hb + (size_t)r * TT + n0 + c8];
        }
        __syncthreads();

        // S = Q K^T (scale folded into q)
        f32x4 s[2][4] = {};
        #pragma unroll
        for (int kq = 0; kq < 2; ++kq) {
            bf16x8 kf[4];
            #pragma unroll
            for (int nt = 0; nt < 4; ++nt)
                kf[nt] = *(const bf16x8*)&Ks[(nt * 16 + lrow) * 72 + kq * 32 + lk * 8];
            #pragma unroll
            for (int mt = 0; mt < 2; ++mt)
                #pragma unroll
                for (int nt = 0; nt < 4; ++nt)
                    s[mt][nt] = __builtin_amdgcn_mfma_f32_16x16x32_bf16(qf[mt][kq], kf[nt], s[mt][nt], 0, 0, 0);
        }

        // causal mask
        if (n0 + 63 > rbase) {
            #pragma unroll
            for (int mt = 0; mt < 2; ++mt)
                #pragma unroll
                for (int nt = 0; nt < 4; ++nt)
                    #pragma unroll
                    for (int r = 0; r < 4; ++r) {
                        int row = rbase + mt * 16 + lk * 4 + r;
                        int col = n0 + nt * 16 + lrow;
                        if (col > row) s[mt][nt][r] = -1e30f;
                    }
        }

        // online softmax per row
        #pragma unroll
        for (int mt = 0; mt < 2; ++mt)
            #pragma unroll
            for (int r = 0; r < 4; ++r) {
                float vmax = fmaxf(fmaxf(s[mt][0][r], s[mt][1][r]), fmaxf(s[mt][2][r], s[mt][3][r]));
                #pragma unroll
                for (int off = 1; off < 16; off <<= 1) vmax = fmaxf(vmax, __shfl_xor(vmax, off, 64));
                float mnew  = fmaxf(mi[mt][r], vmax);
                float alpha = exp2f((mi[mt][r] - mnew) * 1.44269504f);
                float rsum  = 0.f;
                #pragma unroll
                for (int nt = 0; nt < 4; ++nt) {
                    float p = exp2f((s[mt][nt][r] - mnew) * 1.44269504f);
                    s[mt][nt][r] = p; rsum += p;
                }
                #pragma unroll
                for (int off = 1; off < 16; off <<= 1) rsum += __shfl_xor(rsum, off, 64);
                li[mt][r] = li[mt][r] * alpha + rsum;
                mi[mt][r] = mnew;
                #pragma unroll
                for (int dt = 0; dt < 4; ++dt) oacc[mt][dt][r] *= alpha;
            }

        // P -> own wave's LDS region (C/D layout -> A layout transform)
        #pragma unroll
        for (int mt = 0; mt < 2; ++mt)
            #pragma unroll
            for (int nt = 0; nt < 4; ++nt)
                #pragma unroll
                for (int r = 0; r < 4; ++r)
                    PQs[(w * 32 + mt * 16 + lk * 4 + r) * 72 + nt * 16 + lrow] = f2bf(s[mt][nt][r]);

        // O += P V
        #pragma unroll
        for (int kq = 0; kq < 2; ++kq) {
            bf16x8 pf[2], vf[4];
            #pragma unroll
            for (int mt = 0; mt < 2; ++mt)
                pf[mt] = *(const bf16x8*)&PQs[(w * 32 + mt * 16 + lrow) * 72 + kq * 32 + lk * 8];
            #pragma unroll
            for (int dt = 0; dt < 4; ++dt)
                vf[dt] = *(const bf16x8*)&Vts[(dt * 16 + lrow) * 72 + kq * 32 + lk * 8];
            #pragma unroll
            for (int mt = 0; mt < 2; ++mt)
                #pragma unroll
                for (int dt = 0; dt < 4; ++dt)
                    oacc[mt][dt] = __builtin_amdgcn_mfma_f32_16x16x32_bf16(pf[mt], vf[dt], oacc[mt][dt], 0, 0, 0);
        }
    }

    const int b = bh >> 4, h = bh & 15;
    #pragma unroll
    for (int mt = 0; mt < 2; ++mt)
        #pragma unroll
        for (int dt = 0; dt < 4; ++dt)
            #pragma unroll
            for (int r = 0; r < 4; ++r) {
                int row = rbase + mt * 16 + lk * 4 + r;
                int d   = dt * 16 + lrow;
                float inv = 1.f / li[mt][r];
                o[((size_t)(b * TT + row)) * HID + h * HD + d] = f2bf(oacc[mt][dt][r] * inv);
            }
}

extern "C" void kernel_launch(void* const* d_in, const int* in_sizes, int n_in,
                              void* d_out, int out_size, void* d_ws, size_t ws_size,
                              hipStream_t stream) {
    const float* x    = (const float*)d_in[0];
    const float* cosT = (const float*)d_in[1];
    const float* sinT = (const float*)d_in[2];
    const float* wq   = (const float*)d_in[3];
    const float* wk   = (const float*)d_in[4];
    const float* wv   = (const float*)d_in[5];
    const float* wo   = (const float*)d_in[6];
    float* out = (float*)d_out;

    char* ws = (char*)d_ws;
    size_t off = 0;
    u16* x_bf  = (u16*)(ws + off); off += (size_t)BT * HID * 2;      // 16.78 MB (later reused as vt)
    u16* wqkv  = (u16*)(ws + off); off += (size_t)3 * HID * HID * 2; // 6.29 MB
    u16* wo_bf = (u16*)(ws + off); off += (size_t)HID * HID * 2;     // 2.10 MB
    u16* qb    = (u16*)(ws + off); off += (size_t)BT * HID * 2;
    u16* kb    = (u16*)(ws + off); off += (size_t)BT * HID * 2;
    u16* vb    = (u16*)(ws + off); off += (size_t)BT * HID * 2;
    u16* ob    = (u16*)(ws + off); off += (size_t)BT * HID * 2;
    u16* vtb   = x_bf;  // alias: x_bf dead after QKV GEMM, vt written after

    // 1. casts
    cast_kernel<<<(BT * HID / 4 + 255) / 256, 256, 0, stream>>>(x, x_bf, BT * HID / 4);
    cast_kernel<<<1024, 256, 0, stream>>>(wq, wqkv, HID * HID / 4);
    cast_kernel<<<1024, 256, 0, stream>>>(wk, wqkv + (size_t)HID * HID, HID * HID / 4);
    cast_kernel<<<1024, 256, 0, stream>>>(wv, wqkv + (size_t)2 * HID * HID, HID * HID / 4);
    cast_kernel<<<1024, 256, 0, stream>>>(wo, wo_bf, HID * HID / 4);

    // 2. QKV projection (M=8192, N=3072, K=1024)
    gemm_bt<0><<<dim3(BT / 128, 3 * HID / 128), 256, 0, stream>>>(x_bf, wqkv, nullptr, qb, kb, vb);

    // 3. RoPE (q scaled by 1/sqrt(D))
    rope_kernel<<<BH * TT * 32 / 256, 256, 0, stream>>>(qb, kb, cosT, sinT);

    // 4. V transpose -> (B,H,D,T)
    transpose_v<<<dim3(TT / 64, BH), 256, 0, stream>>>(vb, vtb);

    // 5. flash attention -> o (B,T,HID) bf16
    attn_kernel<<<dim3(TT / 128, BH), 256, 0, stream>>>(qb, kb, vtb, ob);

    // 6. output projection (M=8192, N=1024, K=1024) -> fp32
    gemm_bt<1><<<dim3(BT / 128, HID / 128), 256, 0, stream>>>(ob, wo_bf, out, nullptr, nullptr, nullptr);
}